// Round 7
// baseline (219.609 us; speedup 1.0000x reference)
//
#include <hip/hip_runtime.h>
#include <hip/hip_bf16.h>
#include <hip/hip_fp16.h>

// GAT layer on MI355X (gfx950).
//   x: (N=50000, K=256) fp32, W: (K=256, F=64) fp32, a: (1, 128) fp32
//   edge_index: (2, E=1600000) int (src row 0, dst row 1)
// out = elu( segsum_src(e * h[dst]) / segsum_src(e) ),
//   e = exp(-leakyrelu(s_src[src]+s_dst[dst], 0.2)), h = x@W
//
// Round 7:
//  - bin stages packed edges in LDS during its hist pass (one 12.8MB read of
//    src/dst instead of two), BIN_CHUNK 16384.
//  - bsort+gather fused into one block-per-bucket kernel: counting sort and
//    weight pack stay in LDS; sorted_pk/offs global round-trip (12.8MB+launch)
//    deleted.

#define ALPHA 0.2f
#define KDIM 256
#define FDIM 64
#define BIN_CHUNK 16384
#define BUCKET_CAP 4096    // 64-src bucket: mean ~2046 edges; cap is >40 sigma

typedef __bf16 bf16x8 __attribute__((ext_vector_type(8)));
typedef float f32x4 __attribute__((ext_vector_type(4)));
typedef unsigned int u32;
typedef unsigned short u16;

// ---------------------------------------------------------------------------
// Kernel 0: w_t[n][k] = bf16(W[k][n])   (64 x 256 bf16 = 32 KB, L1-resident)
// ---------------------------------------------------------------------------
__global__ __launch_bounds__(256) void gat_wt_kernel(
    const float* __restrict__ W, __hip_bfloat16* __restrict__ w_t)
{
    const int t = blockIdx.x * 256 + threadIdx.x;
    if (t < KDIM * FDIM) {
        const int k = t >> 6;
        const int n = t & 63;
        w_t[n * KDIM + k] = __float2bfloat16(W[t]);
    }
}

// ---------------------------------------------------------------------------
// Kernel 1: h = bf16(x @ W) via mfma_f32_16x16x32_bf16, scores fp32.
// (unchanged since round 3)
// ---------------------------------------------------------------------------
__global__ __launch_bounds__(256) void gat_gemm_kernel(
    const float* __restrict__ x, const __hip_bfloat16* __restrict__ w_tp,
    const float* __restrict__ a, __hip_bfloat16* __restrict__ h_bf,
    float* __restrict__ s_src, float* __restrict__ s_dst, int N)
{
    const int lane = threadIdx.x & 63;
    const int wv = threadIdx.x >> 6;
    const int m0 = blockIdx.x * 64 + wv * 16;
    const int c = lane & 15;
    const int q = lane >> 4;

    const int mrow = m0 + c;
    const float* xp = x + (long)(mrow < N ? mrow : N - 1) * KDIM;
    const __bf16* wt = (const __bf16*)w_tp;

    f32x4 acc[4];
#pragma unroll
    for (int ct = 0; ct < 4; ++ct) acc[ct] = (f32x4){0.f, 0.f, 0.f, 0.f};

#pragma unroll 2
    for (int kc = 0; kc < 8; ++kc) {
        const int k0 = kc * 32 + q * 8;
        const float4 xa = *(const float4*)(xp + k0);
        const float4 xb = *(const float4*)(xp + k0 + 4);
        bf16x8 af;
        af[0] = (__bf16)xa.x; af[1] = (__bf16)xa.y;
        af[2] = (__bf16)xa.z; af[3] = (__bf16)xa.w;
        af[4] = (__bf16)xb.x; af[5] = (__bf16)xb.y;
        af[6] = (__bf16)xb.z; af[7] = (__bf16)xb.w;
#pragma unroll
        for (int ct = 0; ct < 4; ++ct) {
            const bf16x8 bf = *(const bf16x8*)(wt + (ct * 16 + c) * KDIM + k0);
            acc[ct] = __builtin_amdgcn_mfma_f32_16x16x32_bf16(af, bf, acc[ct], 0, 0, 0);
        }
    }

    float a1c[4], a2c[4];
#pragma unroll
    for (int ct = 0; ct < 4; ++ct) {
        a1c[ct] = a[ct * 16 + c];
        a2c[ct] = a[FDIM + ct * 16 + c];
    }
    float s1r[4], s2r[4];
#pragma unroll
    for (int reg = 0; reg < 4; ++reg) {
        float s1 = 0.f, s2 = 0.f;
#pragma unroll
        for (int ct = 0; ct < 4; ++ct) {
            s1 += acc[ct][reg] * a1c[ct];
            s2 += acc[ct][reg] * a2c[ct];
        }
        s1r[reg] = s1; s2r[reg] = s2;
    }
#pragma unroll
    for (int off = 1; off < 16; off <<= 1) {
#pragma unroll
        for (int reg = 0; reg < 4; ++reg) {
            s1r[reg] += __shfl_xor(s1r[reg], off);
            s2r[reg] += __shfl_xor(s2r[reg], off);
        }
    }

#pragma unroll
    for (int reg = 0; reg < 4; ++reg) {
        const int row = m0 + q * 4 + reg;
        if (row < N) {
#pragma unroll
            for (int ct = 0; ct < 4; ++ct)
                h_bf[(long)row * FDIM + ct * 16 + c] = __float2bfloat16(acc[ct][reg]);
            if (c == 0) { s_src[row] = s1r[reg]; s_dst[row] = s2r[reg]; }
        }
    }
}

// ---------------------------------------------------------------------------
// Kernel 2: bucket histogram (bucket = src>>6), LDS-aggregated.
// ---------------------------------------------------------------------------
__global__ __launch_bounds__(256) void gat_bhist_kernel(
    const int* __restrict__ srcA, int* __restrict__ bcnt, int E, int NBU)
{
    __shared__ int hist[1024];
    const int t = threadIdx.x;
    for (int j = t; j < 1024; j += 256) hist[j] = 0;
    __syncthreads();
    const int base = blockIdx.x * BIN_CHUNK;
    const int cnt = min(BIN_CHUNK, E - base);
    for (int i = t; i < cnt; i += 256)
        atomicAdd(&hist[srcA[base + i] >> 6], 1);
    __syncthreads();
    for (int j = t; j < NBU; j += 256) {
        const int v = hist[j];
        if (v) atomicAdd(&bcnt[j], v);
    }
}

// ---------------------------------------------------------------------------
// Kernel 3: exclusive scan of 1024 (padded) bucket counts -> bbase, bcur.
// Single block, 4 elements/thread.
// ---------------------------------------------------------------------------
__global__ __launch_bounds__(256) void gat_bscan_kernel(
    const int* __restrict__ bcnt, int* __restrict__ bbase, int* __restrict__ bcur)
{
    __shared__ int wsum[4];
    const int t = threadIdx.x;
    const int lane = t & 63;
    const int w = t >> 6;
    const int4 v = *(const int4*)&bcnt[4 * t];   // padded region is zero
    const int tsum = v.x + v.y + v.z + v.w;
    int incl = tsum;
#pragma unroll
    for (int off = 1; off < 64; off <<= 1) {
        const int nv = __shfl_up(incl, off);
        if (lane >= off) incl += nv;
    }
    if (lane == 63) wsum[w] = incl;
    __syncthreads();
    int woff = 0;
    if (w > 0) woff += wsum[0];
    if (w > 1) woff += wsum[1];
    if (w > 2) woff += wsum[2];
    const int e0 = woff + incl - tsum;
    const int4 o = make_int4(e0, e0 + v.x, e0 + v.x + v.y, e0 + v.x + v.y + v.z);
    *(int4*)&bbase[4 * t] = o;
    *(int4*)&bcur[4 * t] = o;
    if (t == 255) bbase[1024] = e0 + tsum;   // = E
}

// ---------------------------------------------------------------------------
// Kernel 4: bin. Single read of src/dst, packed staging in LDS, local hist,
// one global reservation atomic per (block,bucket), scatter into bucket-
// contiguous pair[]. Pack = (bucket<<22)|(srclo<<16)|dst.
// ---------------------------------------------------------------------------
__global__ __launch_bounds__(256) void gat_bin_kernel(
    const int* __restrict__ srcA, const int* __restrict__ dstA,
    int* __restrict__ bcur, u32* __restrict__ pair, int E, int NBU)
{
    __shared__ u32 chunk[BIN_CHUNK];   // 64 KB
    __shared__ int hist[1024];
    __shared__ int lcur[1024];
    const int t = threadIdx.x;
    for (int j = t; j < 1024; j += 256) hist[j] = 0;
    __syncthreads();
    const int base = blockIdx.x * BIN_CHUNK;
    const int cnt = min(BIN_CHUNK, E - base);
    for (int i = t; i < cnt; i += 256) {
        const int s = srcA[base + i];
        const int d = dstA[base + i];
        chunk[i] = ((u32)(s >> 6) << 22) | ((u32)(s & 63) << 16) | (u32)d;
        atomicAdd(&hist[s >> 6], 1);
    }
    __syncthreads();
    for (int j = t; j < NBU; j += 256) {
        const int v = hist[j];
        lcur[j] = v ? atomicAdd(&bcur[j], v) : 0;
    }
    __syncthreads();
    for (int i = t; i < cnt; i += 256) {
        const u32 p = chunk[i];
        const int pos = atomicAdd(&lcur[p >> 22], 1);
        pair[pos] = p & 0x003FFFFFu;   // (srclo<<16)|dst
    }
}

// ---------------------------------------------------------------------------
// Kernel 5: fused per-bucket sort + weight pack + segmented gather.
// One block per 64-src bucket. Sort and spk stay in LDS; no sorted_pk/offs
// global arrays. Wave w gathers nodes s0+w*16 .. s0+w*16+15.
// ---------------------------------------------------------------------------
__global__ __launch_bounds__(256) void gat_bgather_kernel(
    const u32* __restrict__ pair, const int* __restrict__ bbase,
    const float* __restrict__ s_src, const float* __restrict__ s_dst,
    const __hip_bfloat16* __restrict__ h_bf, float* __restrict__ out, int N)
{
    __shared__ u32 raw[BUCKET_CAP];   // 16 KB
    __shared__ u32 spk[BUCKET_CAP];   // 16 KB: dst | f16(wgt)<<16, src-sorted
    __shared__ int cur[64];
    __shared__ int seg[65];
    __shared__ float ssl[64];

    const int b = blockIdx.x;
    const int t = threadIdx.x;
    const int s0 = b << 6;
    const int e0 = bbase[b];
    const int e1 = bbase[b + 1];
    const int n = min(e1 - e0, BUCKET_CAP);

    if (t < 64) {
        cur[t] = 0;
        ssl[t] = (s0 + t < N) ? s_src[s0 + t] : 0.f;
    }
    __syncthreads();
    // load + per-src histogram
    for (int i = t; i < n; i += 256) {
        const u32 p = pair[e0 + i];
        raw[i] = p;
        atomicAdd(&cur[p >> 16], 1);
    }
    __syncthreads();
    // wave 0: exclusive scan of 64 per-src counts -> seg[], cursors in cur[]
    if (t < 64) {
        const int v = cur[t];
        int incl = v;
#pragma unroll
        for (int off = 1; off < 64; off <<= 1) {
            const int nv = __shfl_up(incl, off);
            if (t >= off) incl += nv;
        }
        const int excl = incl - v;
        seg[t] = excl;
        cur[t] = excl;
        if (t == 63) seg[64] = incl;
    }
    __syncthreads();
    // sort into spk with weight computed+packed
    for (int i = t; i < n; i += 256) {
        const u32 p = raw[i];
        const int sl = p >> 16;
        const int d = (int)(p & 0xFFFFu);
        const int slot = atomicAdd(&cur[sl], 1);
        const float sc = ssl[sl] + s_dst[d];
        const float lr = sc > 0.f ? sc : ALPHA * sc;
        const float wgt = __expf(-lr);
        const u32 wh = (u32)__half_as_ushort(__float2half(wgt));
        spk[slot] = (u32)d | (wh << 16);
    }
    __syncthreads();

    // gather: wave w handles 16 nodes; 8 edge slots x 8 feature octets
    const int w = t >> 6;
    const int lane = t & 63;
    const int q = lane >> 3;   // edge slot 0..7
    const int c = lane & 7;    // feature octet 0..7
    const __bf16* hb = (const __bf16*)h_bf;

    for (int ln = 0; ln < 16; ++ln) {
        const int nl = w * 16 + ln;          // local node 0..63
        const int node = s0 + nl;
        if (node >= N) break;
        const int start = seg[nl];
        const int end = seg[nl + 1];

        float acc[8];
#pragma unroll
        for (int j = 0; j < 8; ++j) acc[j] = 0.f;
        float wsum = 0.f;

#pragma unroll 2
        for (int e = start + q; e < end; e += 8) {
            const u32 p = spk[e];
            const float wgt = __half2float(__ushort_as_half((u16)(p >> 16)));
            const int d = (int)(p & 0xFFFFu);
            const bf16x8 hv = *(const bf16x8*)(hb + (long)d * FDIM + 8 * c);
#pragma unroll
            for (int j = 0; j < 8; ++j) acc[j] += wgt * (float)hv[j];
            wsum += wgt;
        }

#pragma unroll
        for (int off = 8; off < 64; off <<= 1) {
#pragma unroll
            for (int j = 0; j < 8; ++j) acc[j] += __shfl_xor(acc[j], off);
            wsum += __shfl_xor(wsum, off);
        }

        if (q == 0) {
            const float inv = 1.0f / wsum;
            float o[8];
#pragma unroll
            for (int j = 0; j < 8; ++j) {
                const float v = acc[j] * inv;
                o[j] = v > 0.f ? v : expm1f(v);
            }
            float* op = &out[(long)node * FDIM + 8 * c];
            *(float4*)op = make_float4(o[0], o[1], o[2], o[3]);
            *(float4*)(op + 4) = make_float4(o[4], o[5], o[6], o[7]);
        }
    }
}

extern "C" void kernel_launch(void* const* d_in, const int* in_sizes, int n_in,
                              void* d_out, int out_size, void* d_ws, size_t ws_size,
                              hipStream_t stream) {
    const float* x = (const float*)d_in[0];
    const float* W = (const float*)d_in[1];
    const float* a = (const float*)d_in[2];
    const int* ei  = (const int*)d_in[3];

    const int N = in_sizes[0] / KDIM;       // 50000
    const int E = in_sizes[3] / 2;          // 1600000
    const int NBU = (N + 63) >> 6;          // 782 buckets of 64 srcs
    const int NBLK = (E + BIN_CHUNK - 1) / BIN_CHUNK;  // 98 chunks
    const int* srcA = ei;
    const int* dstA = ei + E;

    // workspace layout (all regions 16B aligned; ~13 MB)
    __hip_bfloat16* h_bf = (__hip_bfloat16*)d_ws;          // N*64 bf16
    __hip_bfloat16* w_t  = h_bf + (size_t)N * FDIM;        // 64*256 bf16
    float* s_src = (float*)(w_t + KDIM * FDIM);            // N
    float* s_dst = s_src + N;                              // N
    int* bcnt    = (int*)(s_dst + N);                      // 1024 (zeroed)
    int* bbase   = bcnt + 1024;                            // 1025 (pad 1028)
    int* bcur    = bbase + 1028;                           // 1024
    u32* pair    = (u32*)(bcur + 1024);                    // E
    float* out   = (float*)d_out;

    hipMemsetAsync(bcnt, 0, 1024 * sizeof(int), stream);

    gat_wt_kernel<<<dim3((KDIM * FDIM + 255) / 256), dim3(256), 0, stream>>>(W, w_t);
    gat_gemm_kernel<<<dim3((N + 63) / 64), dim3(256), 0, stream>>>(
        x, w_t, a, h_bf, s_src, s_dst, N);

    gat_bhist_kernel<<<dim3(NBLK), dim3(256), 0, stream>>>(srcA, bcnt, E, NBU);
    gat_bscan_kernel<<<dim3(1), dim3(256), 0, stream>>>(bcnt, bbase, bcur);
    gat_bin_kernel<<<dim3(NBLK), dim3(256), 0, stream>>>(srcA, dstA, bcur, pair, E, NBU);
    gat_bgather_kernel<<<dim3(NBU), dim3(256), 0, stream>>>(
        pair, bbase, s_src, s_dst, h_bf, out, N);
}

// Round 8
// 212.094 us; speedup vs baseline: 1.0354x; 1.0354x over previous
//
#include <hip/hip_runtime.h>
#include <hip/hip_bf16.h>
#include <hip/hip_fp16.h>

// GAT layer on MI355X (gfx950).
//   x: (N=50000, K=256) fp32, W: (K=256, F=64) fp32, a: (1, 128) fp32
//   edge_index: (2, E=1600000) int (src row 0, dst row 1)
// out = elu( segsum_src(e * h[dst]) / segsum_src(e) ),
//   e = exp(-leakyrelu(s_src[src]+s_dst[dst], 0.2)), h = x@W
//
// Round 8: revert round-7 fusion (bank-conflict + occupancy coupling: 57us
// fused vs 51us split). Round-6 pipeline + ILP in the two latency-bound
// kernels: gemm does 2 row-tiles/wave (4 loads + 8 MFMAs in flight),
// gather runs 2 independent edge streams/lane (16 edges in flight/wave).

#define ALPHA 0.2f
#define KDIM 256
#define FDIM 64
#define BIN_CHUNK 8192
#define BUCKET_CAP 4096    // 64-src bucket: mean ~2046 edges; cap is >40 sigma

typedef __bf16 bf16x8 __attribute__((ext_vector_type(8)));
typedef float f32x4 __attribute__((ext_vector_type(4)));
typedef unsigned int u32;
typedef unsigned short u16;

// ---------------------------------------------------------------------------
// Kernel 0: w_t[n][k] = bf16(W[k][n])   (64 x 256 bf16 = 32 KB, L1-resident)
// ---------------------------------------------------------------------------
__global__ __launch_bounds__(256) void gat_wt_kernel(
    const float* __restrict__ W, __hip_bfloat16* __restrict__ w_t)
{
    const int t = blockIdx.x * 256 + threadIdx.x;
    if (t < KDIM * FDIM) {
        const int k = t >> 6;
        const int n = t & 63;
        w_t[n * KDIM + k] = __float2bfloat16(W[t]);
    }
}

// ---------------------------------------------------------------------------
// Kernel 1: h = bf16(x @ W) via mfma_f32_16x16x32_bf16, scores fp32.
// Round 8: 2 row-tiles per wave (32 rows), shared B-fragments, 128 rows/block.
// ---------------------------------------------------------------------------
__global__ __launch_bounds__(256) void gat_gemm_kernel(
    const float* __restrict__ x, const __hip_bfloat16* __restrict__ w_tp,
    const float* __restrict__ a, __hip_bfloat16* __restrict__ h_bf,
    float* __restrict__ s_src, float* __restrict__ s_dst, int N)
{
    const int lane = threadIdx.x & 63;
    const int wv = threadIdx.x >> 6;
    const int m0 = blockIdx.x * 128 + wv * 32;   // this wave: rows m0..m0+31
    const int c = lane & 15;
    const int q = lane >> 4;

    const int r0 = m0 + c;
    const int r1 = m0 + 16 + c;
    const float* xp0 = x + (long)(r0 < N ? r0 : N - 1) * KDIM;
    const float* xp1 = x + (long)(r1 < N ? r1 : N - 1) * KDIM;
    const __bf16* wt = (const __bf16*)w_tp;

    f32x4 acc[2][4];
#pragma unroll
    for (int rt = 0; rt < 2; ++rt)
#pragma unroll
        for (int ct = 0; ct < 4; ++ct) acc[rt][ct] = (f32x4){0.f, 0.f, 0.f, 0.f};

#pragma unroll 2
    for (int kc = 0; kc < 8; ++kc) {
        const int k0 = kc * 32 + q * 8;
        const float4 xa0 = *(const float4*)(xp0 + k0);
        const float4 xb0 = *(const float4*)(xp0 + k0 + 4);
        const float4 xa1 = *(const float4*)(xp1 + k0);
        const float4 xb1 = *(const float4*)(xp1 + k0 + 4);
        bf16x8 af0, af1;
        af0[0] = (__bf16)xa0.x; af0[1] = (__bf16)xa0.y;
        af0[2] = (__bf16)xa0.z; af0[3] = (__bf16)xa0.w;
        af0[4] = (__bf16)xb0.x; af0[5] = (__bf16)xb0.y;
        af0[6] = (__bf16)xb0.z; af0[7] = (__bf16)xb0.w;
        af1[0] = (__bf16)xa1.x; af1[1] = (__bf16)xa1.y;
        af1[2] = (__bf16)xa1.z; af1[3] = (__bf16)xa1.w;
        af1[4] = (__bf16)xb1.x; af1[5] = (__bf16)xb1.y;
        af1[6] = (__bf16)xb1.z; af1[7] = (__bf16)xb1.w;
#pragma unroll
        for (int ct = 0; ct < 4; ++ct) {
            const bf16x8 bf = *(const bf16x8*)(wt + (ct * 16 + c) * KDIM + k0);
            acc[0][ct] = __builtin_amdgcn_mfma_f32_16x16x32_bf16(af0, bf, acc[0][ct], 0, 0, 0);
            acc[1][ct] = __builtin_amdgcn_mfma_f32_16x16x32_bf16(af1, bf, acc[1][ct], 0, 0, 0);
        }
    }

    float a1c[4], a2c[4];
#pragma unroll
    for (int ct = 0; ct < 4; ++ct) {
        a1c[ct] = a[ct * 16 + c];
        a2c[ct] = a[FDIM + ct * 16 + c];
    }

#pragma unroll
    for (int rt = 0; rt < 2; ++rt) {
        const int mb = m0 + rt * 16;
        float s1r[4], s2r[4];
#pragma unroll
        for (int reg = 0; reg < 4; ++reg) {
            float s1 = 0.f, s2 = 0.f;
#pragma unroll
            for (int ct = 0; ct < 4; ++ct) {
                s1 += acc[rt][ct][reg] * a1c[ct];
                s2 += acc[rt][ct][reg] * a2c[ct];
            }
            s1r[reg] = s1; s2r[reg] = s2;
        }
#pragma unroll
        for (int off = 1; off < 16; off <<= 1) {
#pragma unroll
            for (int reg = 0; reg < 4; ++reg) {
                s1r[reg] += __shfl_xor(s1r[reg], off);
                s2r[reg] += __shfl_xor(s2r[reg], off);
            }
        }
#pragma unroll
        for (int reg = 0; reg < 4; ++reg) {
            const int row = mb + q * 4 + reg;
            if (row < N) {
#pragma unroll
                for (int ct = 0; ct < 4; ++ct)
                    h_bf[(long)row * FDIM + ct * 16 + c] = __float2bfloat16(acc[rt][ct][reg]);
                if (c == 0) { s_src[row] = s1r[reg]; s_dst[row] = s2r[reg]; }
            }
        }
    }
}

// ---------------------------------------------------------------------------
// Kernel 2: bucket histogram (bucket = src>>6), LDS-aggregated.
// ---------------------------------------------------------------------------
__global__ __launch_bounds__(256) void gat_bhist_kernel(
    const int* __restrict__ srcA, int* __restrict__ bcnt, int E, int NBU)
{
    __shared__ int hist[1024];
    const int t = threadIdx.x;
    for (int j = t; j < 1024; j += 256) hist[j] = 0;
    __syncthreads();
    const int base = blockIdx.x * BIN_CHUNK;
    const int cnt = min(BIN_CHUNK, E - base);
    for (int i = t; i < cnt; i += 256)
        atomicAdd(&hist[srcA[base + i] >> 6], 1);
    __syncthreads();
    for (int j = t; j < NBU; j += 256) {
        const int v = hist[j];
        if (v) atomicAdd(&bcnt[j], v);
    }
}

// ---------------------------------------------------------------------------
// Kernel 3: exclusive scan of 1024 (padded) bucket counts -> bbase, bcur.
// ---------------------------------------------------------------------------
__global__ __launch_bounds__(256) void gat_bscan_kernel(
    const int* __restrict__ bcnt, int* __restrict__ bbase, int* __restrict__ bcur)
{
    __shared__ int wsum[4];
    const int t = threadIdx.x;
    const int lane = t & 63;
    const int w = t >> 6;
    const int4 v = *(const int4*)&bcnt[4 * t];   // padded region is zero
    const int tsum = v.x + v.y + v.z + v.w;
    int incl = tsum;
#pragma unroll
    for (int off = 1; off < 64; off <<= 1) {
        const int nv = __shfl_up(incl, off);
        if (lane >= off) incl += nv;
    }
    if (lane == 63) wsum[w] = incl;
    __syncthreads();
    int woff = 0;
    if (w > 0) woff += wsum[0];
    if (w > 1) woff += wsum[1];
    if (w > 2) woff += wsum[2];
    const int e0 = woff + incl - tsum;
    const int4 o = make_int4(e0, e0 + v.x, e0 + v.x + v.y, e0 + v.x + v.y + v.z);
    *(int4*)&bbase[4 * t] = o;
    *(int4*)&bcur[4 * t] = o;
    if (t == 255) bbase[1024] = e0 + tsum;   // = E
}

// ---------------------------------------------------------------------------
// Kernel 4: bin. Local hist, one global reservation atomic per (block,bucket),
// scatter packed (srclo<<16)|dst into bucket-contiguous pair[].
// ---------------------------------------------------------------------------
__global__ __launch_bounds__(256) void gat_bin_kernel(
    const int* __restrict__ srcA, const int* __restrict__ dstA,
    int* __restrict__ bcur, u32* __restrict__ pair, int E, int NBU)
{
    __shared__ int hist[1024];
    __shared__ int lcur[1024];
    const int t = threadIdx.x;
    for (int j = t; j < 1024; j += 256) hist[j] = 0;
    __syncthreads();
    const int base = blockIdx.x * BIN_CHUNK;
    const int cnt = min(BIN_CHUNK, E - base);
    for (int i = t; i < cnt; i += 256)
        atomicAdd(&hist[srcA[base + i] >> 6], 1);
    __syncthreads();
    for (int j = t; j < NBU; j += 256) {
        const int v = hist[j];
        lcur[j] = v ? atomicAdd(&bcur[j], v) : 0;
    }
    __syncthreads();
    for (int i = t; i < cnt; i += 256) {
        const int s = srcA[base + i];
        const int d = dstA[base + i];
        const int pos = atomicAdd(&lcur[s >> 6], 1);
        pair[pos] = ((u32)(s & 63) << 16) | (u32)d;   // d < 65536
    }
}

// ---------------------------------------------------------------------------
// Kernel 5: per-bucket LDS counting sort + weight pack. One block per 64-src
// bucket (16 KB LDS). Emits offs[] (CSR) and sorted_pk = dst | f16(wgt)<<16.
// ---------------------------------------------------------------------------
__global__ __launch_bounds__(256) void gat_bsort_kernel(
    const u32* __restrict__ pair, const int* __restrict__ bbase,
    const float* __restrict__ s_src, const float* __restrict__ s_dst,
    int* __restrict__ offs, u32* __restrict__ sorted_pk, int N, int NBU)
{
    __shared__ u32 chunk[BUCKET_CAP];   // 16 KB
    __shared__ int cur[64];
    __shared__ float ssl[64];

    const int b = blockIdx.x;
    const int t = threadIdx.x;
    const int s0 = b << 6;
    const int e0 = bbase[b];
    const int e1 = bbase[b + 1];
    const int n = min(e1 - e0, BUCKET_CAP);

    if (t < 64) {
        cur[t] = 0;
        ssl[t] = (s0 + t < N) ? s_src[s0 + t] : 0.f;
    }
    __syncthreads();
    for (int i = t; i < n; i += 256) {
        const u32 p = pair[e0 + i];
        chunk[i] = p;
        atomicAdd(&cur[p >> 16], 1);
    }
    __syncthreads();
    if (t < 64) {   // wave 0: exclusive scan of 64 counts
        const int v = cur[t];
        int incl = v;
#pragma unroll
        for (int off = 1; off < 64; off <<= 1) {
            const int nv = __shfl_up(incl, off);
            if (t >= off) incl += nv;
        }
        const int excl = incl - v;
        if (s0 + t < N) offs[s0 + t] = e0 + excl;
        cur[t] = excl;
    }
    if (b == NBU - 1 && t == 0) offs[N] = e1;
    __syncthreads();
    for (int i = t; i < n; i += 256) {
        const u32 p = chunk[i];
        const int sl = p >> 16;
        const int d = (int)(p & 0xFFFFu);
        const int slot = atomicAdd(&cur[sl], 1);
        const float sc = ssl[sl] + s_dst[d];
        const float lr = sc > 0.f ? sc : ALPHA * sc;
        const float wgt = __expf(-lr);
        const u32 wh = (u32)__half_as_ushort(__float2half(wgt));
        sorted_pk[e0 + slot] = (u32)d | (wh << 16);
    }
}

// ---------------------------------------------------------------------------
// Kernel 6: segmented reduction over bf16 h. One wave per node; 8 edge slots
// x 8 feature octets; Round 8: 2 independent edge streams per lane
// (16 edges in flight per wave) to hide L2/L3 gather latency.
// ---------------------------------------------------------------------------
__global__ __launch_bounds__(256) void gat_gather_kernel(
    const int* __restrict__ offs, const u32* __restrict__ sorted_pk,
    const __hip_bfloat16* __restrict__ h_bf, float* __restrict__ out, int N)
{
    const int node = blockIdx.x * 4 + (threadIdx.x >> 6);
    if (node >= N) return;
    const int lane = threadIdx.x & 63;
    const int q = lane >> 3;   // edge slot 0..7
    const int c = lane & 7;    // feature octet 0..7

    const int start = offs[node];
    const int end = offs[node + 1];
    const __bf16* hb = (const __bf16*)h_bf;

    float acc0[8], acc1[8];
#pragma unroll
    for (int j = 0; j < 8; ++j) { acc0[j] = 0.f; acc1[j] = 0.f; }
    float wsum0 = 0.f, wsum1 = 0.f;

    int e = start + q;
    for (; e + 8 < end; e += 16) {
        const u32 p0 = sorted_pk[e];
        const u32 p1 = sorted_pk[e + 8];
        const int d0 = (int)(p0 & 0xFFFFu);
        const int d1 = (int)(p1 & 0xFFFFu);
        const bf16x8 hv0 = *(const bf16x8*)(hb + (long)d0 * FDIM + 8 * c);
        const bf16x8 hv1 = *(const bf16x8*)(hb + (long)d1 * FDIM + 8 * c);
        const float w0 = __half2float(__ushort_as_half((u16)(p0 >> 16)));
        const float w1 = __half2float(__ushort_as_half((u16)(p1 >> 16)));
#pragma unroll
        for (int j = 0; j < 8; ++j) {
            acc0[j] += w0 * (float)hv0[j];
            acc1[j] += w1 * (float)hv1[j];
        }
        wsum0 += w0;
        wsum1 += w1;
    }
    if (e < end) {
        const u32 p0 = sorted_pk[e];
        const int d0 = (int)(p0 & 0xFFFFu);
        const bf16x8 hv0 = *(const bf16x8*)(hb + (long)d0 * FDIM + 8 * c);
        const float w0 = __half2float(__ushort_as_half((u16)(p0 >> 16)));
#pragma unroll
        for (int j = 0; j < 8; ++j) acc0[j] += w0 * (float)hv0[j];
        wsum0 += w0;
    }

    float acc[8];
#pragma unroll
    for (int j = 0; j < 8; ++j) acc[j] = acc0[j] + acc1[j];
    float wsum = wsum0 + wsum1;

#pragma unroll
    for (int off = 8; off < 64; off <<= 1) {
#pragma unroll
        for (int j = 0; j < 8; ++j) acc[j] += __shfl_xor(acc[j], off);
        wsum += __shfl_xor(wsum, off);
    }

    if (q == 0) {
        const float inv = 1.0f / wsum;
        float o[8];
#pragma unroll
        for (int j = 0; j < 8; ++j) {
            const float v = acc[j] * inv;
            o[j] = v > 0.f ? v : expm1f(v);
        }
        float* op = &out[(long)node * FDIM + 8 * c];
        *(float4*)op = make_float4(o[0], o[1], o[2], o[3]);
        *(float4*)(op + 4) = make_float4(o[4], o[5], o[6], o[7]);
    }
}

extern "C" void kernel_launch(void* const* d_in, const int* in_sizes, int n_in,
                              void* d_out, int out_size, void* d_ws, size_t ws_size,
                              hipStream_t stream) {
    const float* x = (const float*)d_in[0];
    const float* W = (const float*)d_in[1];
    const float* a = (const float*)d_in[2];
    const int* ei  = (const int*)d_in[3];

    const int N = in_sizes[0] / KDIM;       // 50000
    const int E = in_sizes[3] / 2;          // 1600000
    const int NBU = (N + 63) >> 6;          // 782 buckets of 64 srcs
    const int NBLK = (E + BIN_CHUNK - 1) / BIN_CHUNK;  // 196 chunks
    const int* srcA = ei;
    const int* dstA = ei + E;

    // workspace layout (all regions 16B aligned; ~20 MB)
    __hip_bfloat16* h_bf = (__hip_bfloat16*)d_ws;          // N*64 bf16
    __hip_bfloat16* w_t  = h_bf + (size_t)N * FDIM;        // 64*256 bf16
    float* s_src = (float*)(w_t + KDIM * FDIM);            // N
    float* s_dst = s_src + N;                              // N
    int* offs    = (int*)(s_dst + N);                      // N+1 (pad N+4)
    int* bcnt    = offs + N + 4;                           // 1024 (zeroed)
    int* bbase   = bcnt + 1024;                            // 1025 (pad 1028)
    int* bcur    = bbase + 1028;                           // 1024
    u32* pair    = (u32*)(bcur + 1024);                    // E
    u32* sorted_pk = pair + E;                             // E
    float* out   = (float*)d_out;

    hipMemsetAsync(bcnt, 0, 1024 * sizeof(int), stream);

    gat_wt_kernel<<<dim3((KDIM * FDIM + 255) / 256), dim3(256), 0, stream>>>(W, w_t);
    gat_gemm_kernel<<<dim3((N + 127) / 128), dim3(256), 0, stream>>>(
        x, w_t, a, h_bf, s_src, s_dst, N);

    gat_bhist_kernel<<<dim3(NBLK), dim3(256), 0, stream>>>(srcA, bcnt, E, NBU);
    gat_bscan_kernel<<<dim3(1), dim3(256), 0, stream>>>(bcnt, bbase, bcur);
    gat_bin_kernel<<<dim3(NBLK), dim3(256), 0, stream>>>(srcA, dstA, bcur, pair, E, NBU);
    gat_bsort_kernel<<<dim3(NBU), dim3(256), 0, stream>>>(
        pair, bbase, s_src, s_dst, offs, sorted_pk, N, NBU);

    gat_gather_kernel<<<dim3((N + 3) / 4), dim3(256), 0, stream>>>(
        offs, sorted_pk, h_bf, out, N);
}

// Round 9
// 190.084 us; speedup vs baseline: 1.1553x; 1.1158x over previous
//
#include <hip/hip_runtime.h>
#include <hip/hip_bf16.h>
#include <hip/hip_fp16.h>

// GAT layer on MI355X (gfx950).
//   x: (N=50000, K=256) fp32, W: (K=256, F=64) fp32, a: (1, 128) fp32
//   edge_index: (2, E=1600000) int (src row 0, dst row 1)
// out = elu( segsum_src(e * h[dst]) / segsum_src(e) ),
//   e = exp(-leakyrelu(s_src[src]+s_dst[dst], 0.2)), h = x@W
//
// Round 9: fixed-stride bucket arena. pair[] / sorted_pk[] give each 64-src
// bucket a private CAP-sized slot, so bin reserves space with atomicAdd from
// zero and the bhist/bscan kernels (one full 6.4MB src read + scan + 2
// launches) are deleted. bsort emits arena-based per-node [nstart,nend).

#define ALPHA 0.2f
#define KDIM 256
#define FDIM 64
#define BIN_CHUNK 8192
#define BUCKET_CAP 4096    // 64-src bucket: mean ~2046 edges; >40 sigma slack

typedef __bf16 bf16x8 __attribute__((ext_vector_type(8)));
typedef float f32x4 __attribute__((ext_vector_type(4)));
typedef unsigned int u32;
typedef unsigned short u16;

// ---------------------------------------------------------------------------
// Kernel 0: w_t[n][k] = bf16(W[k][n])   (64 x 256 bf16 = 32 KB, L1-resident)
// ---------------------------------------------------------------------------
__global__ __launch_bounds__(256) void gat_wt_kernel(
    const float* __restrict__ W, __hip_bfloat16* __restrict__ w_t)
{
    const int t = blockIdx.x * 256 + threadIdx.x;
    if (t < KDIM * FDIM) {
        const int k = t >> 6;
        const int n = t & 63;
        w_t[n * KDIM + k] = __float2bfloat16(W[t]);
    }
}

// ---------------------------------------------------------------------------
// Kernel 1: h = bf16(x @ W) via mfma_f32_16x16x32_bf16, scores fp32.
// 2 row-tiles per wave (32 rows), shared B-fragments, 128 rows/block.
// ---------------------------------------------------------------------------
__global__ __launch_bounds__(256) void gat_gemm_kernel(
    const float* __restrict__ x, const __hip_bfloat16* __restrict__ w_tp,
    const float* __restrict__ a, __hip_bfloat16* __restrict__ h_bf,
    float* __restrict__ s_src, float* __restrict__ s_dst, int N)
{
    const int lane = threadIdx.x & 63;
    const int wv = threadIdx.x >> 6;
    const int m0 = blockIdx.x * 128 + wv * 32;   // this wave: rows m0..m0+31
    const int c = lane & 15;
    const int q = lane >> 4;

    const int r0 = m0 + c;
    const int r1 = m0 + 16 + c;
    const float* xp0 = x + (long)(r0 < N ? r0 : N - 1) * KDIM;
    const float* xp1 = x + (long)(r1 < N ? r1 : N - 1) * KDIM;
    const __bf16* wt = (const __bf16*)w_tp;

    f32x4 acc[2][4];
#pragma unroll
    for (int rt = 0; rt < 2; ++rt)
#pragma unroll
        for (int ct = 0; ct < 4; ++ct) acc[rt][ct] = (f32x4){0.f, 0.f, 0.f, 0.f};

#pragma unroll 2
    for (int kc = 0; kc < 8; ++kc) {
        const int k0 = kc * 32 + q * 8;
        const float4 xa0 = *(const float4*)(xp0 + k0);
        const float4 xb0 = *(const float4*)(xp0 + k0 + 4);
        const float4 xa1 = *(const float4*)(xp1 + k0);
        const float4 xb1 = *(const float4*)(xp1 + k0 + 4);
        bf16x8 af0, af1;
        af0[0] = (__bf16)xa0.x; af0[1] = (__bf16)xa0.y;
        af0[2] = (__bf16)xa0.z; af0[3] = (__bf16)xa0.w;
        af0[4] = (__bf16)xb0.x; af0[5] = (__bf16)xb0.y;
        af0[6] = (__bf16)xb0.z; af0[7] = (__bf16)xb0.w;
        af1[0] = (__bf16)xa1.x; af1[1] = (__bf16)xa1.y;
        af1[2] = (__bf16)xa1.z; af1[3] = (__bf16)xa1.w;
        af1[4] = (__bf16)xb1.x; af1[5] = (__bf16)xb1.y;
        af1[6] = (__bf16)xb1.z; af1[7] = (__bf16)xb1.w;
#pragma unroll
        for (int ct = 0; ct < 4; ++ct) {
            const bf16x8 bf = *(const bf16x8*)(wt + (ct * 16 + c) * KDIM + k0);
            acc[0][ct] = __builtin_amdgcn_mfma_f32_16x16x32_bf16(af0, bf, acc[0][ct], 0, 0, 0);
            acc[1][ct] = __builtin_amdgcn_mfma_f32_16x16x32_bf16(af1, bf, acc[1][ct], 0, 0, 0);
        }
    }

    float a1c[4], a2c[4];
#pragma unroll
    for (int ct = 0; ct < 4; ++ct) {
        a1c[ct] = a[ct * 16 + c];
        a2c[ct] = a[FDIM + ct * 16 + c];
    }

#pragma unroll
    for (int rt = 0; rt < 2; ++rt) {
        const int mb = m0 + rt * 16;
        float s1r[4], s2r[4];
#pragma unroll
        for (int reg = 0; reg < 4; ++reg) {
            float s1 = 0.f, s2 = 0.f;
#pragma unroll
            for (int ct = 0; ct < 4; ++ct) {
                s1 += acc[rt][ct][reg] * a1c[ct];
                s2 += acc[rt][ct][reg] * a2c[ct];
            }
            s1r[reg] = s1; s2r[reg] = s2;
        }
#pragma unroll
        for (int off = 1; off < 16; off <<= 1) {
#pragma unroll
            for (int reg = 0; reg < 4; ++reg) {
                s1r[reg] += __shfl_xor(s1r[reg], off);
                s2r[reg] += __shfl_xor(s2r[reg], off);
            }
        }
#pragma unroll
        for (int reg = 0; reg < 4; ++reg) {
            const int row = mb + q * 4 + reg;
            if (row < N) {
#pragma unroll
                for (int ct = 0; ct < 4; ++ct)
                    h_bf[(long)row * FDIM + ct * 16 + c] = __float2bfloat16(acc[rt][ct][reg]);
                if (c == 0) { s_src[row] = s1r[reg]; s_dst[row] = s2r[reg]; }
            }
        }
    }
}

// ---------------------------------------------------------------------------
// Kernel 2: bin into fixed-stride arena. Local hist, one reservation atomic
// per (block,bucket) on zero-initialized bcur, scatter packed
// (srclo<<16)|dst into pair[b*CAP + slot].
// ---------------------------------------------------------------------------
__global__ __launch_bounds__(256) void gat_bin_kernel(
    const int* __restrict__ srcA, const int* __restrict__ dstA,
    int* __restrict__ bcur, u32* __restrict__ pair, int E, int NBU)
{
    __shared__ int hist[1024];
    __shared__ int lcur[1024];
    const int t = threadIdx.x;
    for (int j = t; j < 1024; j += 256) hist[j] = 0;
    __syncthreads();
    const int base = blockIdx.x * BIN_CHUNK;
    const int cnt = min(BIN_CHUNK, E - base);
    for (int i = t; i < cnt; i += 256)
        atomicAdd(&hist[srcA[base + i] >> 6], 1);
    __syncthreads();
    for (int j = t; j < NBU; j += 256) {
        const int v = hist[j];
        lcur[j] = v ? (j * BUCKET_CAP + atomicAdd(&bcur[j], v)) : 0;
    }
    __syncthreads();
    for (int i = t; i < cnt; i += 256) {
        const int s = srcA[base + i];
        const int d = dstA[base + i];
        const int pos = atomicAdd(&lcur[s >> 6], 1);
        pair[pos] = ((u32)(s & 63) << 16) | (u32)d;   // d < 65536
    }
}

// ---------------------------------------------------------------------------
// Kernel 3: per-bucket LDS counting sort + weight pack. One block per 64-src
// bucket (16 KB LDS). Count comes from bcur[b]. Emits per-node [nstart,nend)
// and sorted_pk = dst | f16(wgt)<<16 in the bucket's arena slot.
// ---------------------------------------------------------------------------
__global__ __launch_bounds__(256) void gat_bsort_kernel(
    const u32* __restrict__ pair, const int* __restrict__ bcur,
    const float* __restrict__ s_src, const float* __restrict__ s_dst,
    int* __restrict__ nstart, int* __restrict__ nend,
    u32* __restrict__ sorted_pk, int N)
{
    __shared__ u32 chunk[BUCKET_CAP];   // 16 KB
    __shared__ int cur[64];
    __shared__ float ssl[64];

    const int b = blockIdx.x;
    const int t = threadIdx.x;
    const int s0 = b << 6;
    const int abase = b * BUCKET_CAP;
    const int n = min(bcur[b], BUCKET_CAP);

    if (t < 64) {
        cur[t] = 0;
        ssl[t] = (s0 + t < N) ? s_src[s0 + t] : 0.f;
    }
    __syncthreads();
    for (int i = t; i < n; i += 256) {
        const u32 p = pair[abase + i];
        chunk[i] = p;
        atomicAdd(&cur[p >> 16], 1);
    }
    __syncthreads();
    if (t < 64) {   // wave 0: exclusive scan of 64 counts
        const int v = cur[t];
        int incl = v;
#pragma unroll
        for (int off = 1; off < 64; off <<= 1) {
            const int nv = __shfl_up(incl, off);
            if (t >= off) incl += nv;
        }
        const int excl = incl - v;
        if (s0 + t < N) {
            nstart[s0 + t] = abase + excl;
            nend[s0 + t] = abase + excl + v;
        }
        cur[t] = excl;
    }
    __syncthreads();
    for (int i = t; i < n; i += 256) {
        const u32 p = chunk[i];
        const int sl = p >> 16;
        const int d = (int)(p & 0xFFFFu);
        const int slot = atomicAdd(&cur[sl], 1);
        const float sc = ssl[sl] + s_dst[d];
        const float lr = sc > 0.f ? sc : ALPHA * sc;
        const float wgt = __expf(-lr);
        const u32 wh = (u32)__half_as_ushort(__float2half(wgt));
        sorted_pk[abase + slot] = (u32)d | (wh << 16);
    }
}

// ---------------------------------------------------------------------------
// Kernel 4: segmented reduction over bf16 h. One wave per node; 8 edge slots
// x 8 feature octets; 2 independent edge streams per lane.
// ---------------------------------------------------------------------------
__global__ __launch_bounds__(256) void gat_gather_kernel(
    const int* __restrict__ nstart, const int* __restrict__ nend,
    const u32* __restrict__ sorted_pk,
    const __hip_bfloat16* __restrict__ h_bf, float* __restrict__ out, int N)
{
    const int node = blockIdx.x * 4 + (threadIdx.x >> 6);
    if (node >= N) return;
    const int lane = threadIdx.x & 63;
    const int q = lane >> 3;   // edge slot 0..7
    const int c = lane & 7;    // feature octet 0..7

    const int start = nstart[node];
    const int end = nend[node];
    const __bf16* hb = (const __bf16*)h_bf;

    float acc0[8], acc1[8];
#pragma unroll
    for (int j = 0; j < 8; ++j) { acc0[j] = 0.f; acc1[j] = 0.f; }
    float wsum0 = 0.f, wsum1 = 0.f;

    int e = start + q;
    for (; e + 8 < end; e += 16) {
        const u32 p0 = sorted_pk[e];
        const u32 p1 = sorted_pk[e + 8];
        const int d0 = (int)(p0 & 0xFFFFu);
        const int d1 = (int)(p1 & 0xFFFFu);
        const bf16x8 hv0 = *(const bf16x8*)(hb + (long)d0 * FDIM + 8 * c);
        const bf16x8 hv1 = *(const bf16x8*)(hb + (long)d1 * FDIM + 8 * c);
        const float w0 = __half2float(__ushort_as_half((u16)(p0 >> 16)));
        const float w1 = __half2float(__ushort_as_half((u16)(p1 >> 16)));
#pragma unroll
        for (int j = 0; j < 8; ++j) {
            acc0[j] += w0 * (float)hv0[j];
            acc1[j] += w1 * (float)hv1[j];
        }
        wsum0 += w0;
        wsum1 += w1;
    }
    if (e < end) {
        const u32 p0 = sorted_pk[e];
        const int d0 = (int)(p0 & 0xFFFFu);
        const bf16x8 hv0 = *(const bf16x8*)(hb + (long)d0 * FDIM + 8 * c);
        const float w0 = __half2float(__ushort_as_half((u16)(p0 >> 16)));
#pragma unroll
        for (int j = 0; j < 8; ++j) acc0[j] += w0 * (float)hv0[j];
        wsum0 += w0;
    }

    float acc[8];
#pragma unroll
    for (int j = 0; j < 8; ++j) acc[j] = acc0[j] + acc1[j];
    float wsum = wsum0 + wsum1;

#pragma unroll
    for (int off = 8; off < 64; off <<= 1) {
#pragma unroll
        for (int j = 0; j < 8; ++j) acc[j] += __shfl_xor(acc[j], off);
        wsum += __shfl_xor(wsum, off);
    }

    if (q == 0) {
        const float inv = 1.0f / wsum;
        float o[8];
#pragma unroll
        for (int j = 0; j < 8; ++j) {
            const float v = acc[j] * inv;
            o[j] = v > 0.f ? v : expm1f(v);
        }
        float* op = &out[(long)node * FDIM + 8 * c];
        *(float4*)op = make_float4(o[0], o[1], o[2], o[3]);
        *(float4*)(op + 4) = make_float4(o[4], o[5], o[6], o[7]);
    }
}

extern "C" void kernel_launch(void* const* d_in, const int* in_sizes, int n_in,
                              void* d_out, int out_size, void* d_ws, size_t ws_size,
                              hipStream_t stream) {
    const float* x = (const float*)d_in[0];
    const float* W = (const float*)d_in[1];
    const float* a = (const float*)d_in[2];
    const int* ei  = (const int*)d_in[3];

    const int N = in_sizes[0] / KDIM;       // 50000
    const int E = in_sizes[3] / 2;          // 1600000
    const int NBU = (N + 63) >> 6;          // 782 buckets of 64 srcs
    const int NBLK = (E + BIN_CHUNK - 1) / BIN_CHUNK;  // 196 chunks
    const int* srcA = ei;
    const int* dstA = ei + E;

    // workspace layout (all regions 16B aligned; ~33 MB)
    __hip_bfloat16* h_bf = (__hip_bfloat16*)d_ws;          // N*64 bf16
    __hip_bfloat16* w_t  = h_bf + (size_t)N * FDIM;        // 64*256 bf16
    float* s_src = (float*)(w_t + KDIM * FDIM);            // N
    float* s_dst = s_src + N;                              // N
    int* nstart  = (int*)(s_dst + N);                      // N
    int* nend    = nstart + N;                             // N
    int* bcur    = nend + N;                               // 1024 (zeroed)
    u32* pair    = (u32*)(bcur + 1024);                    // NBU*CAP arena
    u32* sorted_pk = pair + (size_t)NBU * BUCKET_CAP;      // NBU*CAP arena
    float* out   = (float*)d_out;

    hipMemsetAsync(bcur, 0, 1024 * sizeof(int), stream);

    gat_wt_kernel<<<dim3((KDIM * FDIM + 255) / 256), dim3(256), 0, stream>>>(W, w_t);
    gat_gemm_kernel<<<dim3((N + 127) / 128), dim3(256), 0, stream>>>(
        x, w_t, a, h_bf, s_src, s_dst, N);

    gat_bin_kernel<<<dim3(NBLK), dim3(256), 0, stream>>>(srcA, dstA, bcur, pair, E, NBU);
    gat_bsort_kernel<<<dim3(NBU), dim3(256), 0, stream>>>(
        pair, bcur, s_src, s_dst, nstart, nend, sorted_pk, N);

    gat_gather_kernel<<<dim3((N + 3) / 4), dim3(256), 0, stream>>>(
        nstart, nend, sorted_pk, h_bf, out, N);
}

// Round 10
// 172.535 us; speedup vs baseline: 1.2728x; 1.1017x over previous
//
#include <hip/hip_runtime.h>
#include <hip/hip_bf16.h>
#include <hip/hip_fp16.h>

// GAT layer on MI355X (gfx950).
//   x: (N=50000, K=256) fp32, W: (K=256, F=64) fp32, a: (1, 128) fp32
//   edge_index: (2, E=1600000) int (src row 0, dst row 1)
// out = elu( segsum_src(e * h[dst]) / segsum_src(e) ),
//   e = exp(-leakyrelu(s_src[src]+s_dst[dst], 0.2)), h = x@W
//
// Round 10: bin (latency-bound, 7% occupancy, 196 blocks idling most CUs)
// and gemm (BW/MFMA-bound) have no data dependency -> fused into ONE fat
// kernel so their waves co-schedule across all 256 CUs. BIN_CHUNK halved to
// 4096 (391 bin blocks, halved per-block critical path). bcur memset folded
// into the wt kernel. bsort/gather unchanged from round 9.

#define ALPHA 0.2f
#define KDIM 256
#define FDIM 64
#define BIN_CHUNK 4096
#define BUCKET_CAP 4096    // 64-src bucket: mean ~2046 edges; >40 sigma slack

typedef __bf16 bf16x8 __attribute__((ext_vector_type(8)));
typedef float f32x4 __attribute__((ext_vector_type(4)));
typedef unsigned int u32;
typedef unsigned short u16;

// ---------------------------------------------------------------------------
// Kernel 0: w_t[n][k] = bf16(W[k][n]) (32 KB, L1-resident) + zero bcur.
// ---------------------------------------------------------------------------
__global__ __launch_bounds__(256) void gat_wt_kernel(
    const float* __restrict__ W, __hip_bfloat16* __restrict__ w_t,
    int* __restrict__ bcur)
{
    const int t = blockIdx.x * 256 + threadIdx.x;
    if (t < KDIM * FDIM) {
        const int k = t >> 6;
        const int n = t & 63;
        w_t[n * KDIM + k] = __float2bfloat16(W[t]);
    }
    if (t < 1024) bcur[t] = 0;
}

// ---------------------------------------------------------------------------
// Kernel 1 (fused): blocks [0,NBLK) = bin; blocks [NBLK, NBLK+GB) = gemm.
//
// bin: local hist, one reservation atomic per (block,bucket) on bcur,
//      scatter packed (srclo<<16)|dst into arena pair[b*CAP + slot].
// gemm: h = bf16(x @ W) via mfma_f32_16x16x32_bf16, scores fp32;
//       2 row-tiles per wave (32 rows), 128 rows/block.
// ---------------------------------------------------------------------------
__global__ __launch_bounds__(256) void gat_gemm_bin_kernel(
    const float* __restrict__ x, const __hip_bfloat16* __restrict__ w_tp,
    const float* __restrict__ a, __hip_bfloat16* __restrict__ h_bf,
    float* __restrict__ s_src, float* __restrict__ s_dst,
    const int* __restrict__ srcA, const int* __restrict__ dstA,
    int* __restrict__ bcur, u32* __restrict__ pair,
    int N, int E, int NBU, int NBLK)
{
    __shared__ int hist[1024];
    __shared__ int lcur[1024];

    const int t = threadIdx.x;

    if ((int)blockIdx.x < NBLK) {
        // ---------------- bin path ----------------
        for (int j = t; j < 1024; j += 256) hist[j] = 0;
        __syncthreads();
        const int base = blockIdx.x * BIN_CHUNK;
        const int cnt = min(BIN_CHUNK, E - base);
        for (int i = t; i < cnt; i += 256)
            atomicAdd(&hist[srcA[base + i] >> 6], 1);
        __syncthreads();
        for (int j = t; j < NBU; j += 256) {
            const int v = hist[j];
            lcur[j] = v ? (j * BUCKET_CAP + atomicAdd(&bcur[j], v)) : 0;
        }
        __syncthreads();
        for (int i = t; i < cnt; i += 256) {
            const int s = srcA[base + i];
            const int d = dstA[base + i];
            const int pos = atomicAdd(&lcur[s >> 6], 1);
            pair[pos] = ((u32)(s & 63) << 16) | (u32)d;   // d < 65536
        }
        return;
    }

    // ---------------- gemm path ----------------
    const int gb = (int)blockIdx.x - NBLK;
    const int lane = t & 63;
    const int wv = t >> 6;
    const int m0 = gb * 128 + wv * 32;   // this wave: rows m0..m0+31
    const int c = lane & 15;
    const int q = lane >> 4;

    const int r0 = m0 + c;
    const int r1 = m0 + 16 + c;
    const float* xp0 = x + (long)(r0 < N ? r0 : N - 1) * KDIM;
    const float* xp1 = x + (long)(r1 < N ? r1 : N - 1) * KDIM;
    const __bf16* wt = (const __bf16*)w_tp;

    f32x4 acc[2][4];
#pragma unroll
    for (int rt = 0; rt < 2; ++rt)
#pragma unroll
        for (int ct = 0; ct < 4; ++ct) acc[rt][ct] = (f32x4){0.f, 0.f, 0.f, 0.f};

#pragma unroll 2
    for (int kc = 0; kc < 8; ++kc) {
        const int k0 = kc * 32 + q * 8;
        const float4 xa0 = *(const float4*)(xp0 + k0);
        const float4 xb0 = *(const float4*)(xp0 + k0 + 4);
        const float4 xa1 = *(const float4*)(xp1 + k0);
        const float4 xb1 = *(const float4*)(xp1 + k0 + 4);
        bf16x8 af0, af1;
        af0[0] = (__bf16)xa0.x; af0[1] = (__bf16)xa0.y;
        af0[2] = (__bf16)xa0.z; af0[3] = (__bf16)xa0.w;
        af0[4] = (__bf16)xb0.x; af0[5] = (__bf16)xb0.y;
        af0[6] = (__bf16)xb0.z; af0[7] = (__bf16)xb0.w;
        af1[0] = (__bf16)xa1.x; af1[1] = (__bf16)xa1.y;
        af1[2] = (__bf16)xa1.z; af1[3] = (__bf16)xa1.w;
        af1[4] = (__bf16)xb1.x; af1[5] = (__bf16)xb1.y;
        af1[6] = (__bf16)xb1.z; af1[7] = (__bf16)xb1.w;
#pragma unroll
        for (int ct = 0; ct < 4; ++ct) {
            const bf16x8 bf = *(const bf16x8*)(wt + (ct * 16 + c) * KDIM + k0);
            acc[0][ct] = __builtin_amdgcn_mfma_f32_16x16x32_bf16(af0, bf, acc[0][ct], 0, 0, 0);
            acc[1][ct] = __builtin_amdgcn_mfma_f32_16x16x32_bf16(af1, bf, acc[1][ct], 0, 0, 0);
        }
    }

    float a1c[4], a2c[4];
#pragma unroll
    for (int ct = 0; ct < 4; ++ct) {
        a1c[ct] = a[ct * 16 + c];
        a2c[ct] = a[FDIM + ct * 16 + c];
    }

#pragma unroll
    for (int rt = 0; rt < 2; ++rt) {
        const int mb = m0 + rt * 16;
        float s1r[4], s2r[4];
#pragma unroll
        for (int reg = 0; reg < 4; ++reg) {
            float s1 = 0.f, s2 = 0.f;
#pragma unroll
            for (int ct = 0; ct < 4; ++ct) {
                s1 += acc[rt][ct][reg] * a1c[ct];
                s2 += acc[rt][ct][reg] * a2c[ct];
            }
            s1r[reg] = s1; s2r[reg] = s2;
        }
#pragma unroll
        for (int off = 1; off < 16; off <<= 1) {
#pragma unroll
            for (int reg = 0; reg < 4; ++reg) {
                s1r[reg] += __shfl_xor(s1r[reg], off);
                s2r[reg] += __shfl_xor(s2r[reg], off);
            }
        }
#pragma unroll
        for (int reg = 0; reg < 4; ++reg) {
            const int row = mb + q * 4 + reg;
            if (row < N) {
#pragma unroll
                for (int ct = 0; ct < 4; ++ct)
                    h_bf[(long)row * FDIM + ct * 16 + c] = __float2bfloat16(acc[rt][ct][reg]);
                if (c == 0) { s_src[row] = s1r[reg]; s_dst[row] = s2r[reg]; }
            }
        }
    }
}

// ---------------------------------------------------------------------------
// Kernel 2: per-bucket LDS counting sort + weight pack. One block per 64-src
// bucket (16 KB LDS). Count from bcur[b]. Emits per-node [nstart,nend) and
// sorted_pk = dst | f16(wgt)<<16 in the bucket's arena slot.
// ---------------------------------------------------------------------------
__global__ __launch_bounds__(256) void gat_bsort_kernel(
    const u32* __restrict__ pair, const int* __restrict__ bcur,
    const float* __restrict__ s_src, const float* __restrict__ s_dst,
    int* __restrict__ nstart, int* __restrict__ nend,
    u32* __restrict__ sorted_pk, int N)
{
    __shared__ u32 chunk[BUCKET_CAP];   // 16 KB
    __shared__ int cur[64];
    __shared__ float ssl[64];

    const int b = blockIdx.x;
    const int t = threadIdx.x;
    const int s0 = b << 6;
    const int abase = b * BUCKET_CAP;
    const int n = min(bcur[b], BUCKET_CAP);

    if (t < 64) {
        cur[t] = 0;
        ssl[t] = (s0 + t < N) ? s_src[s0 + t] : 0.f;
    }
    __syncthreads();
    for (int i = t; i < n; i += 256) {
        const u32 p = pair[abase + i];
        chunk[i] = p;
        atomicAdd(&cur[p >> 16], 1);
    }
    __syncthreads();
    if (t < 64) {   // wave 0: exclusive scan of 64 counts
        const int v = cur[t];
        int incl = v;
#pragma unroll
        for (int off = 1; off < 64; off <<= 1) {
            const int nv = __shfl_up(incl, off);
            if (t >= off) incl += nv;
        }
        const int excl = incl - v;
        if (s0 + t < N) {
            nstart[s0 + t] = abase + excl;
            nend[s0 + t] = abase + excl + v;
        }
        cur[t] = excl;
    }
    __syncthreads();
    for (int i = t; i < n; i += 256) {
        const u32 p = chunk[i];
        const int sl = p >> 16;
        const int d = (int)(p & 0xFFFFu);
        const int slot = atomicAdd(&cur[sl], 1);
        const float sc = ssl[sl] + s_dst[d];
        const float lr = sc > 0.f ? sc : ALPHA * sc;
        const float wgt = __expf(-lr);
        const u32 wh = (u32)__half_as_ushort(__float2half(wgt));
        sorted_pk[abase + slot] = (u32)d | (wh << 16);
    }
}

// ---------------------------------------------------------------------------
// Kernel 3: segmented reduction over bf16 h. One wave per node; 8 edge slots
// x 8 feature octets; 2 independent edge streams per lane.
// ---------------------------------------------------------------------------
__global__ __launch_bounds__(256) void gat_gather_kernel(
    const int* __restrict__ nstart, const int* __restrict__ nend,
    const u32* __restrict__ sorted_pk,
    const __hip_bfloat16* __restrict__ h_bf, float* __restrict__ out, int N)
{
    const int node = blockIdx.x * 4 + (threadIdx.x >> 6);
    if (node >= N) return;
    const int lane = threadIdx.x & 63;
    const int q = lane >> 3;   // edge slot 0..7
    const int c = lane & 7;    // feature octet 0..7

    const int start = nstart[node];
    const int end = nend[node];
    const __bf16* hb = (const __bf16*)h_bf;

    float acc0[8], acc1[8];
#pragma unroll
    for (int j = 0; j < 8; ++j) { acc0[j] = 0.f; acc1[j] = 0.f; }
    float wsum0 = 0.f, wsum1 = 0.f;

    int e = start + q;
    for (; e + 8 < end; e += 16) {
        const u32 p0 = sorted_pk[e];
        const u32 p1 = sorted_pk[e + 8];
        const int d0 = (int)(p0 & 0xFFFFu);
        const int d1 = (int)(p1 & 0xFFFFu);
        const bf16x8 hv0 = *(const bf16x8*)(hb + (long)d0 * FDIM + 8 * c);
        const bf16x8 hv1 = *(const bf16x8*)(hb + (long)d1 * FDIM + 8 * c);
        const float w0 = __half2float(__ushort_as_half((u16)(p0 >> 16)));
        const float w1 = __half2float(__ushort_as_half((u16)(p1 >> 16)));
#pragma unroll
        for (int j = 0; j < 8; ++j) {
            acc0[j] += w0 * (float)hv0[j];
            acc1[j] += w1 * (float)hv1[j];
        }
        wsum0 += w0;
        wsum1 += w1;
    }
    if (e < end) {
        const u32 p0 = sorted_pk[e];
        const int d0 = (int)(p0 & 0xFFFFu);
        const bf16x8 hv0 = *(const bf16x8*)(hb + (long)d0 * FDIM + 8 * c);
        const float w0 = __half2float(__ushort_as_half((u16)(p0 >> 16)));
#pragma unroll
        for (int j = 0; j < 8; ++j) acc0[j] += w0 * (float)hv0[j];
        wsum0 += w0;
    }

    float acc[8];
#pragma unroll
    for (int j = 0; j < 8; ++j) acc[j] = acc0[j] + acc1[j];
    float wsum = wsum0 + wsum1;

#pragma unroll
    for (int off = 8; off < 64; off <<= 1) {
#pragma unroll
        for (int j = 0; j < 8; ++j) acc[j] += __shfl_xor(acc[j], off);
        wsum += __shfl_xor(wsum, off);
    }

    if (q == 0) {
        const float inv = 1.0f / wsum;
        float o[8];
#pragma unroll
        for (int j = 0; j < 8; ++j) {
            const float v = acc[j] * inv;
            o[j] = v > 0.f ? v : expm1f(v);
        }
        float* op = &out[(long)node * FDIM + 8 * c];
        *(float4*)op = make_float4(o[0], o[1], o[2], o[3]);
        *(float4*)(op + 4) = make_float4(o[4], o[5], o[6], o[7]);
    }
}

extern "C" void kernel_launch(void* const* d_in, const int* in_sizes, int n_in,
                              void* d_out, int out_size, void* d_ws, size_t ws_size,
                              hipStream_t stream) {
    const float* x = (const float*)d_in[0];
    const float* W = (const float*)d_in[1];
    const float* a = (const float*)d_in[2];
    const int* ei  = (const int*)d_in[3];

    const int N = in_sizes[0] / KDIM;       // 50000
    const int E = in_sizes[3] / 2;          // 1600000
    const int NBU = (N + 63) >> 6;          // 782 buckets of 64 srcs
    const int NBLK = (E + BIN_CHUNK - 1) / BIN_CHUNK;  // 391 bin chunks
    const int GB = (N + 127) / 128;                    // 391 gemm blocks
    const int* srcA = ei;
    const int* dstA = ei + E;

    // workspace layout (all regions 16B aligned; ~33 MB)
    __hip_bfloat16* h_bf = (__hip_bfloat16*)d_ws;          // N*64 bf16
    __hip_bfloat16* w_t  = h_bf + (size_t)N * FDIM;        // 64*256 bf16
    float* s_src = (float*)(w_t + KDIM * FDIM);            // N
    float* s_dst = s_src + N;                              // N
    int* nstart  = (int*)(s_dst + N);                      // N
    int* nend    = nstart + N;                             // N
    int* bcur    = nend + N;                               // 1024 (zeroed by wt)
    u32* pair    = (u32*)(bcur + 1024);                    // NBU*CAP arena
    u32* sorted_pk = pair + (size_t)NBU * BUCKET_CAP;      // NBU*CAP arena
    float* out   = (float*)d_out;

    gat_wt_kernel<<<dim3((KDIM * FDIM + 255) / 256), dim3(256), 0, stream>>>(
        W, w_t, bcur);

    gat_gemm_bin_kernel<<<dim3(NBLK + GB), dim3(256), 0, stream>>>(
        x, w_t, a, h_bf, s_src, s_dst, srcA, dstA, bcur, pair, N, E, NBU, NBLK);

    gat_bsort_kernel<<<dim3(NBU), dim3(256), 0, stream>>>(
        pair, bcur, s_src, s_dst, nstart, nend, sorted_pk, N);

    gat_gather_kernel<<<dim3((N + 3) / 4), dim3(256), 0, stream>>>(
        nstart, nend, sorted_pk, h_bf, out, N);
}